// Round 12
// baseline (177.302 us; speedup 1.0000x reference)
//
#include <hip/hip_runtime.h>

#define NNODES 50000
#define NEDGES 800000
#define FDIM 128
#define HDIM 128
#define CDIM 16

#define NBUCK 256
#define BCAP 6144   // per-bucket capacity: mean 4096, sd 64 -> 32 sigma headroom
#define NBA 391     // binA blocks: ceil(800000/2048)
#define NMB 782     // mask-pack blocks: ceil(200000/256)
#define NHB 512     // half-bucket blocks: 2 per bucket (node halves)

typedef __attribute__((ext_vector_type(8))) short bf16x8;
typedef __attribute__((ext_vector_type(4))) float f32x4;

__device__ __forceinline__ ushort f32_to_bf16_rne(float f) {
  unsigned u = __float_as_uint(f);
  unsigned rounded = u + 0x7fffu + ((u >> 16) & 1u);
  return (ushort)(rounded >> 16);
}
__device__ __forceinline__ float bf_lo(unsigned u) { return __uint_as_float(u << 16); }
__device__ __forceinline__ float bf_hi(unsigned u) { return __uint_as_float(u & 0xffff0000u); }

// ---------------- kernel 1: binA (blocks < NBA) + mask bit-pack (rest) -----
// mask values are exactly {0.0, 2.0} (dropout pre-scaled by 1/keep) -> 1 bit.
__global__ __launch_bounds__(256) void k_binA(
    const int* __restrict__ src, const int* __restrict__ dst,
    int* __restrict__ gcur, unsigned* __restrict__ ebuf,
    const float* __restrict__ mask, unsigned* __restrict__ maskb) {
  __shared__ int cnt[NBUCK];
  __shared__ int base[NBUCK];
  int tid = threadIdx.x;
  if (blockIdx.x < NBA) {
    int e0 = blockIdx.x * 2048;
    cnt[tid] = 0;
    __syncthreads();
    int sv[8], dv[8];
    #pragma unroll
    for (int i = 0; i < 8; ++i) {
      int e = e0 + i * 256 + tid;
      if (e < NEDGES) {
        sv[i] = src[e];
        dv[i] = dst[e];
        atomicAdd(&cnt[dv[i] >> 8], 1);
      } else {
        dv[i] = -1;
      }
    }
    __syncthreads();
    base[tid] = atomicAdd(&gcur[tid], cnt[tid]);  // bucket-relative base
    cnt[tid] = 0;  // reuse as local cursor
    __syncthreads();
    #pragma unroll
    for (int i = 0; i < 8; ++i) {
      if (dv[i] >= 0) {
        int b = dv[i] >> 8;
        int pos = base[b] + atomicAdd(&cnt[b], 1);
        if (pos < BCAP)  // safety clamp (statistically impossible)
          ebuf[b * BCAP + pos] = ((unsigned)(dv[i] & 255) << 16) | (unsigned)sv[i];
      }
    }
    return;
  }
  // ---- mask pack: one thread per 32 channels ----
  int t = (blockIdx.x - NBA) * 256 + tid;
  if (t < 200000) {
    const float* mp = mask + (size_t)t * 32;
    unsigned bits = 0;
    #pragma unroll
    for (int i = 0; i < 8; ++i) {
      float4 m = *reinterpret_cast<const float4*>(mp + i * 4);
      bits |= (m.x != 0.f ? 1u : 0u) << (i * 4 + 0);
      bits |= (m.y != 0.f ? 1u : 0u) << (i * 4 + 1);
      bits |= (m.z != 0.f ? 1u : 0u) << (i * 4 + 2);
      bits |= (m.w != 0.f ? 1u : 0u) << (i * 4 + 3);
    }
    maskb[t] = bits;
  }
}

// ---------------- kernel 2: half-bucket CSR finalize + casts ---------------
// CHANGE vs R5: each bucket is processed by TWO blocks (node halves), so the
// serial per-block chain (count pass + scans + scatter) halves and 2 blocks/CU
// overlap. Both halves read the full bucket edge list (2x ebuf reads = +6.3MB,
// ~1us); hi-half's within-bucket base = lo-half edge count, computed in-pass.
__global__ __launch_bounds__(256) void k_binB_cast(
    const int* __restrict__ gcur, const unsigned* __restrict__ ebuf,
    int* __restrict__ deg, int* __restrict__ offs, ushort* __restrict__ ssrc,
    const float* __restrict__ x, ushort* __restrict__ xh,
    const float* __restrict__ W1, ushort* __restrict__ W1T,
    const float* __restrict__ W2, ushort* __restrict__ W2T) {
  __shared__ int s[NBUCK];
  __shared__ int doffh[128];
  __shared__ int dcur[128];
  __shared__ int lo_total;
  int tid = threadIdx.x;
  if (blockIdx.x < NHB) {
    int b = blockIdx.x >> 1;
    int hf = blockIdx.x & 1;
    int c = gcur[tid];
    if (c > BCAP) c = BCAP;
    s[tid] = c;
    for (int off = 1; off < 256; off <<= 1) {
      __syncthreads();
      int t = (tid >= off) ? s[tid - off] : 0;
      __syncthreads();
      s[tid] += t;
    }
    __syncthreads();
    int my_base = (b > 0) ? s[b - 1] : 0;  // bucket's global exclusive prefix
    int count = s[b] - my_base;

    if (tid < 128) dcur[tid] = 0;
    if (tid == 0) lo_total = 0;
    __syncthreads();
    const unsigned* eb = &ebuf[b * BCAP];
    int myLo = 0;
    for (int e = tid; e < count; e += 256) {
      int loc = eb[e] >> 16;
      myLo += (loc < 128) ? 1 : 0;
      if ((loc >> 7) == hf) atomicAdd(&dcur[loc & 127], 1);
    }
    if (myLo) atomicAdd(&lo_total, myLo);
    __syncthreads();
    int dn = (tid < 128) ? dcur[tid] : 0;
    s[tid] = dn;
    for (int off = 1; off < 256; off <<= 1) {
      __syncthreads();
      int t = (tid >= off) ? s[tid - off] : 0;
      __syncthreads();
      s[tid] += t;
    }
    __syncthreads();
    int base_in = hf ? lo_total : 0;
    if (tid < 128) {
      doffh[tid] = s[tid] - dn;  // exclusive within half
      int node = b * 256 + hf * 128 + tid;
      if (node < NNODES) {
        deg[node] = dn;
        offs[node] = my_base + base_in + doffh[tid];
      }
      dcur[tid] = 0;
    }
    __syncthreads();
    for (int e = tid; e < count; e += 256) {
      unsigned v = eb[e];
      int loc = v >> 16;
      if ((loc >> 7) == hf) {
        int l = loc & 127;
        int pos = my_base + base_in + doffh[l] + atomicAdd(&dcur[l], 1);
        ssrc[pos] = (ushort)(v & 0xffffu);
      }
    }
    return;
  }
  // ---- cast range ----
  int t = (blockIdx.x - NHB) * 256 + tid;
  if (t < 1600000) {  // x -> bf16, linear layout
    float4 v = *reinterpret_cast<const float4*>(&x[t * 4]);
    ushort4 o;
    o.x = f32_to_bf16_rne(v.x);
    o.y = f32_to_bf16_rne(v.y);
    o.z = f32_to_bf16_rne(v.z);
    o.w = f32_to_bf16_rne(v.w);
    *reinterpret_cast<ushort4*>(&xh[t * 4]) = o;
    return;
  }
  t -= 1600000;
  if (t < 16384) {  // W1T[c][k] = bf16(W1[k][c])
    int c = t >> 7, k = t & 127;
    W1T[c * 128 + k] = f32_to_bf16_rne(W1[k * 128 + c]);
    return;
  }
  t -= 16384;
  if (t < 2048) {  // W2T[c][k] = bf16(W2[k][c])
    int c = t >> 7, k = t & 127;
    W2T[c * 128 + k] = f32_to_bf16_rne(W2[k * 16 + c]);
  }
}

// ------ fused layer1 + dense (exact R5 kernel, fastest measured: 43.1us) ---
#define HT_STRIDE 132  // shorts; 2-way bank aliasing on b64/b128 (free)
__global__ __launch_bounds__(256) void k_fused1(
    const ushort* __restrict__ xh, const int* __restrict__ offs,
    const int* __restrict__ deg, const ushort* __restrict__ ssrc,
    const ushort* __restrict__ W1T, const float* __restrict__ b1,
    const unsigned* __restrict__ maskb, const ushort* __restrict__ W2T,
    ushort* __restrict__ zh) {
  __shared__ ushort sh[16 * HT_STRIDE];  // agg tile [node][ch]
  __shared__ ushort ht[16 * HT_STRIDE];  // h tile [node][ch]
  int tid = threadIdx.x;
  int grp = tid >> 4;   // node within block (0..15)
  int l16 = tid & 15;   // channel group: ch [8*l16, 8*l16+8)
  int nw = blockIdx.x * 16;
  int n = nw + grp;     // always < NNODES (3125*16 == 50000)
  int start = offs[n];
  int d = deg[n];
  const ushort* base = xh + l16 * 8;
  float a0[8] = {0,0,0,0,0,0,0,0};
  float a1[8] = {0,0,0,0,0,0,0,0};
  float a2[8] = {0,0,0,0,0,0,0,0};
  float a3[8] = {0,0,0,0,0,0,0,0};
  int j = 0;
  for (; j + 3 < d; j += 4) {
    int s0 = ssrc[start + j + 0];
    int s1 = ssrc[start + j + 1];
    int s2 = ssrc[start + j + 2];
    int s3 = ssrc[start + j + 3];
    uint4 u0 = *reinterpret_cast<const uint4*>(base + s0 * FDIM);
    uint4 u1 = *reinterpret_cast<const uint4*>(base + s1 * FDIM);
    uint4 u2 = *reinterpret_cast<const uint4*>(base + s2 * FDIM);
    uint4 u3 = *reinterpret_cast<const uint4*>(base + s3 * FDIM);
    a0[0] += bf_lo(u0.x); a0[1] += bf_hi(u0.x); a0[2] += bf_lo(u0.y); a0[3] += bf_hi(u0.y);
    a0[4] += bf_lo(u0.z); a0[5] += bf_hi(u0.z); a0[6] += bf_lo(u0.w); a0[7] += bf_hi(u0.w);
    a1[0] += bf_lo(u1.x); a1[1] += bf_hi(u1.x); a1[2] += bf_lo(u1.y); a1[3] += bf_hi(u1.y);
    a1[4] += bf_lo(u1.z); a1[5] += bf_hi(u1.z); a1[6] += bf_lo(u1.w); a1[7] += bf_hi(u1.w);
    a2[0] += bf_lo(u2.x); a2[1] += bf_hi(u2.x); a2[2] += bf_lo(u2.y); a2[3] += bf_hi(u2.y);
    a2[4] += bf_lo(u2.z); a2[5] += bf_hi(u2.z); a2[6] += bf_lo(u2.w); a2[7] += bf_hi(u2.w);
    a3[0] += bf_lo(u3.x); a3[1] += bf_hi(u3.x); a3[2] += bf_lo(u3.y); a3[3] += bf_hi(u3.y);
    a3[4] += bf_lo(u3.z); a3[5] += bf_hi(u3.z); a3[6] += bf_lo(u3.w); a3[7] += bf_hi(u3.w);
  }
  for (; j < d; ++j) {
    int s0 = ssrc[start + j];
    uint4 u0 = *reinterpret_cast<const uint4*>(base + s0 * FDIM);
    a0[0] += bf_lo(u0.x); a0[1] += bf_hi(u0.x); a0[2] += bf_lo(u0.y); a0[3] += bf_hi(u0.y);
    a0[4] += bf_lo(u0.z); a0[5] += bf_hi(u0.z); a0[6] += bf_lo(u0.w); a0[7] += bf_hi(u0.w);
  }
  float inv = 1.0f / (float)(d > 0 ? d : 1);
  unsigned r[4];
  #pragma unroll
  for (int k = 0; k < 4; ++k) {
    float e0 = (a0[2 * k] + a1[2 * k] + a2[2 * k] + a3[2 * k]) * inv;
    float e1 = (a0[2 * k + 1] + a1[2 * k + 1] + a2[2 * k + 1] + a3[2 * k + 1]) * inv;
    r[k] = (unsigned)f32_to_bf16_rne(e0) | ((unsigned)f32_to_bf16_rne(e1) << 16);
  }
  *reinterpret_cast<uint4*>(&sh[grp * HT_STRIDE + l16 * 8]) =
      (uint4){r[0], r[1], r[2], r[3]};
  __syncthreads();

  // ---- GEMM1: wave w computes ct = 2w, 2w+1 ----
  int w = tid >> 6;
  int lane = tid & 63;
  int m = lane & 15, quad = lane >> 4;
  int ct0 = 2 * w, ct1 = 2 * w + 1;

  bf16x8 af[4];
  #pragma unroll
  for (int kk = 0; kk < 4; ++kk) {
    const ushort* ap = &sh[m * HT_STRIDE + kk * 32 + quad * 8];
    ushort4 alo = *reinterpret_cast<const ushort4*>(ap);
    ushort4 ahi = *reinterpret_cast<const ushort4*>(ap + 4);
    af[kk] = (bf16x8){(short)alo.x, (short)alo.y, (short)alo.z, (short)alo.w,
                      (short)ahi.x, (short)ahi.y, (short)ahi.z, (short)ahi.w};
  }
  f32x4 acc0 = (f32x4){0.f, 0.f, 0.f, 0.f};
  f32x4 acc1 = (f32x4){0.f, 0.f, 0.f, 0.f};
  const ushort* bp0 = &W1T[(size_t)(ct0 * 16 + m) * 128 + quad * 8];
  const ushort* bp1 = &W1T[(size_t)(ct1 * 16 + m) * 128 + quad * 8];
  #pragma unroll
  for (int kk = 0; kk < 4; ++kk) {
    acc0 = __builtin_amdgcn_mfma_f32_16x16x32_bf16(
        af[kk], *reinterpret_cast<const bf16x8*>(bp0 + kk * 32), acc0, 0, 0, 0);
    acc1 = __builtin_amdgcn_mfma_f32_16x16x32_bf16(
        af[kk], *reinterpret_cast<const bf16x8*>(bp1 + kk * 32), acc1, 0, 0, 0);
  }

  // mask words for this wave's two 32-ch blocks: word index = ct>>1 = w
  unsigned mbw[4];
  #pragma unroll
  for (int rr = 0; rr < 4; ++rr) {
    mbw[rr] = maskb[(size_t)(nw + quad * 4 + rr) * 4 + w];
  }
  float bb0 = b1[ct0 * 16 + m];
  float bb1 = b1[ct1 * 16 + m];
  int sh0 = m;        // (ct0&1)=0 -> shift = m
  int sh1 = 16 + m;   // (ct1&1)=1 -> shift = 16+m
  #pragma unroll
  for (int rr = 0; rr < 4; ++rr) {
    float v0 = acc0[rr] + bb0;
    v0 = v0 > 0.f ? v0 : 0.f;
    v0 = ((mbw[rr] >> sh0) & 1u) ? (v0 + v0) : 0.f;
    ht[(quad * 4 + rr) * HT_STRIDE + ct0 * 16 + m] = f32_to_bf16_rne(v0);
    float v1 = acc1[rr] + bb1;
    v1 = v1 > 0.f ? v1 : 0.f;
    v1 = ((mbw[rr] >> sh1) & 1u) ? (v1 + v1) : 0.f;
    ht[(quad * 4 + rr) * HT_STRIDE + ct1 * 16 + m] = f32_to_bf16_rne(v1);
  }
  __syncthreads();

  // ---- GEMM2 (wave 0 only): z_tile[16n x 16c] = ht @ W2 ----
  if (w == 0) {
    f32x4 zacc = (f32x4){0.f, 0.f, 0.f, 0.f};
    #pragma unroll
    for (int kk = 0; kk < 4; ++kk) {
      const ushort* ap = &ht[m * HT_STRIDE + kk * 32 + quad * 8];
      ushort4 alo = *reinterpret_cast<const ushort4*>(ap);
      ushort4 ahi = *reinterpret_cast<const ushort4*>(ap + 4);
      bf16x8 afr = (bf16x8){(short)alo.x, (short)alo.y, (short)alo.z, (short)alo.w,
                            (short)ahi.x, (short)ahi.y, (short)ahi.z, (short)ahi.w};
      bf16x8 b2f = *reinterpret_cast<const bf16x8*>(&W2T[m * 128 + kk * 32 + quad * 8]);
      zacc = __builtin_amdgcn_mfma_f32_16x16x32_bf16(afr, b2f, zacc, 0, 0, 0);
    }
    #pragma unroll
    for (int rr = 0; rr < 4; ++rr) {
      zh[(size_t)(nw + quad * 4 + rr) * 16 + m] = f32_to_bf16_rne(zacc[rr]);
    }
  }
}

// ---------------- layer 2 aggregate + bias: out = mean(z) + b2 ----------------
__global__ __launch_bounds__(256) void k_spmm2(
    const ushort* __restrict__ zh, const int* __restrict__ offs,
    const int* __restrict__ deg, const ushort* __restrict__ ssrc,
    const float* __restrict__ b2, float* __restrict__ out) {
  int tid = threadIdx.x;
  int nl = tid >> 3, c2 = tid & 7;  // node-local, channel pair
  int n = blockIdx.x * 32 + nl;
  if (n >= NNODES) return;
  int start = offs[n], d = deg[n];
  const ushort* zb = zh + c2 * 2;
  float a0 = 0.f, a1 = 0.f, b0 = 0.f, b1v = 0.f;
  float c0 = 0.f, c1 = 0.f, d0 = 0.f, d1 = 0.f;
  int j = 0;
  for (; j + 7 < d; j += 8) {
    int s0 = ssrc[start + j + 0], s1 = ssrc[start + j + 1];
    int s2 = ssrc[start + j + 2], s3 = ssrc[start + j + 3];
    int s4 = ssrc[start + j + 4], s5 = ssrc[start + j + 5];
    int s6 = ssrc[start + j + 6], s7 = ssrc[start + j + 7];
    unsigned u0 = *reinterpret_cast<const unsigned*>(zb + s0 * 16);
    unsigned u1 = *reinterpret_cast<const unsigned*>(zb + s1 * 16);
    unsigned u2 = *reinterpret_cast<const unsigned*>(zb + s2 * 16);
    unsigned u3 = *reinterpret_cast<const unsigned*>(zb + s3 * 16);
    unsigned u4 = *reinterpret_cast<const unsigned*>(zb + s4 * 16);
    unsigned u5 = *reinterpret_cast<const unsigned*>(zb + s5 * 16);
    unsigned u6 = *reinterpret_cast<const unsigned*>(zb + s6 * 16);
    unsigned u7 = *reinterpret_cast<const unsigned*>(zb + s7 * 16);
    a0 += bf_lo(u0); a1 += bf_hi(u0);
    b0 += bf_lo(u1); b1v += bf_hi(u1);
    c0 += bf_lo(u2); c1 += bf_hi(u2);
    d0 += bf_lo(u3); d1 += bf_hi(u3);
    a0 += bf_lo(u4); a1 += bf_hi(u4);
    b0 += bf_lo(u5); b1v += bf_hi(u5);
    c0 += bf_lo(u6); c1 += bf_hi(u6);
    d0 += bf_lo(u7); d1 += bf_hi(u7);
  }
  for (; j < d; ++j) {
    int s0 = ssrc[start + j];
    unsigned u0 = *reinterpret_cast<const unsigned*>(zb + s0 * 16);
    a0 += bf_lo(u0); a1 += bf_hi(u0);
  }
  float inv = 1.0f / (float)(d > 0 ? d : 1);
  float o0 = ((a0 + b0) + (c0 + d0)) * inv + b2[c2 * 2 + 0];
  float o1 = ((a1 + b1v) + (c1 + d1)) * inv + b2[c2 * 2 + 1];
  float2 o; o.x = o0; o.y = o1;
  *reinterpret_cast<float2*>(&out[(size_t)n * 16 + c2 * 2]) = o;
}

// ---------------- launch ----------------

extern "C" void kernel_launch(void* const* d_in, const int* in_sizes, int n_in,
                              void* d_out, int out_size, void* d_ws, size_t ws_size,
                              hipStream_t stream) {
  const float* x    = (const float*)d_in[0];
  const int*   ei   = (const int*)d_in[1];
  const float* W1   = (const float*)d_in[2];
  const float* b1   = (const float*)d_in[3];
  const float* W2   = (const float*)d_in[4];
  const float* b2   = (const float*)d_in[5];
  const float* mask = (const float*)d_in[6];
  float* out = (float*)d_out;

  const int* src = ei;            // edge_index[0]
  const int* dst = ei + NEDGES;   // edge_index[1]

  char* ws = (char*)d_ws;
  size_t o = 0;
  auto alloc = [&](size_t bytes) -> void* {
    void* p = ws + o;
    o += (bytes + 255) & ~(size_t)255;
    return p;
  };
  ushort*   xh    = (ushort*)alloc((size_t)NNODES * 128 * 2);
  ushort*   zh    = (ushort*)alloc((size_t)NNODES * 16 * 2);
  ushort*   W1T   = (ushort*)alloc((size_t)128 * 128 * 2);
  ushort*   W2T   = (ushort*)alloc((size_t)16 * 128 * 2);
  int*      deg   = (int*)alloc((size_t)NNODES * 4);
  int*      offs  = (int*)alloc((size_t)NNODES * 4);
  int*      gcur  = (int*)alloc((size_t)NBUCK * 4);
  unsigned* ebuf  = (unsigned*)alloc((size_t)NBUCK * BCAP * 4);
  ushort*   ssrc  = (ushort*)alloc((size_t)NEDGES * 2);
  unsigned* maskb = (unsigned*)alloc((size_t)NNODES * 4 * 4);

  int cast_blocks = (1600000 + 16384 + 2048 + 255) / 256;

  hipMemsetAsync(gcur, 0, NBUCK * sizeof(int), stream);
  k_binA<<<NBA + NMB, 256, 0, stream>>>(src, dst, gcur, ebuf, mask, maskb);
  k_binB_cast<<<NHB + cast_blocks, 256, 0, stream>>>(gcur, ebuf, deg, offs, ssrc,
                                                     x, xh, W1, W1T, W2, W2T);
  k_fused1<<<NNODES / 16, 256, 0, stream>>>(xh, offs, deg, ssrc,
                                            W1T, b1, maskb, W2T, zh);
  k_spmm2<<<(NNODES + 31) / 32, 256, 0, stream>>>(zh, offs, deg, ssrc, b2, out);
}

// Round 13
// 171.796 us; speedup vs baseline: 1.0321x; 1.0321x over previous
//
#include <hip/hip_runtime.h>

#define NNODES 50000
#define NEDGES 800000
#define FDIM 128
#define HDIM 128
#define CDIM 16

#define NBUCK 256
#define BCAP 6144   // per-bucket capacity: mean 4096, sd 64 -> 32 sigma headroom
#define NBA 391     // binA blocks: ceil(800000/2048)
#define NMB 782     // mask-pack blocks: ceil(200000/256)

typedef __attribute__((ext_vector_type(8))) short bf16x8;
typedef __attribute__((ext_vector_type(4))) float f32x4;

__device__ __forceinline__ ushort f32_to_bf16_rne(float f) {
  unsigned u = __float_as_uint(f);
  unsigned rounded = u + 0x7fffu + ((u >> 16) & 1u);
  return (ushort)(rounded >> 16);
}
__device__ __forceinline__ float bf_lo(unsigned u) { return __uint_as_float(u << 16); }
__device__ __forceinline__ float bf_hi(unsigned u) { return __uint_as_float(u & 0xffff0000u); }

// ---------------- kernel 1: binA (blocks < NBA) + mask bit-pack (rest) -----
// mask values are exactly {0.0, 2.0} (dropout pre-scaled by 1/keep) -> 1 bit.
__global__ __launch_bounds__(256) void k_binA(
    const int* __restrict__ src, const int* __restrict__ dst,
    int* __restrict__ gcur, unsigned* __restrict__ ebuf,
    const float* __restrict__ mask, unsigned* __restrict__ maskb) {
  __shared__ int cnt[NBUCK];
  __shared__ int base[NBUCK];
  int tid = threadIdx.x;
  if (blockIdx.x < NBA) {
    int e0 = blockIdx.x * 2048;
    cnt[tid] = 0;
    __syncthreads();
    int sv[8], dv[8];
    #pragma unroll
    for (int i = 0; i < 8; ++i) {
      int e = e0 + i * 256 + tid;
      if (e < NEDGES) {
        sv[i] = src[e];
        dv[i] = dst[e];
        atomicAdd(&cnt[dv[i] >> 8], 1);
      } else {
        dv[i] = -1;
      }
    }
    __syncthreads();
    base[tid] = atomicAdd(&gcur[tid], cnt[tid]);  // bucket-relative base
    cnt[tid] = 0;  // reuse as local cursor
    __syncthreads();
    #pragma unroll
    for (int i = 0; i < 8; ++i) {
      if (dv[i] >= 0) {
        int b = dv[i] >> 8;
        int pos = base[b] + atomicAdd(&cnt[b], 1);
        if (pos < BCAP)  // safety clamp (statistically impossible)
          ebuf[b * BCAP + pos] = ((unsigned)(dv[i] & 255) << 16) | (unsigned)sv[i];
      }
    }
    return;
  }
  // ---- mask pack: one thread per 32 channels ----
  int t = (blockIdx.x - NBA) * 256 + tid;
  if (t < 200000) {
    const float* mp = mask + (size_t)t * 32;
    unsigned bits = 0;
    #pragma unroll
    for (int i = 0; i < 8; ++i) {
      float4 m = *reinterpret_cast<const float4*>(mp + i * 4);
      bits |= (m.x != 0.f ? 1u : 0u) << (i * 4 + 0);
      bits |= (m.y != 0.f ? 1u : 0u) << (i * 4 + 1);
      bits |= (m.z != 0.f ? 1u : 0u) << (i * 4 + 2);
      bits |= (m.w != 0.f ? 1u : 0u) << (i * 4 + 3);
    }
    maskb[t] = bits;
  }
}

// ---------------- kernel 2: binB buckets (blocks < NBUCK) + casts (rest) ---
__global__ __launch_bounds__(256) void k_binB_cast(
    const int* __restrict__ gcur, const unsigned* __restrict__ ebuf,
    int* __restrict__ deg, int* __restrict__ offs, ushort* __restrict__ ssrc,
    const float* __restrict__ x, ushort* __restrict__ xh,
    const float* __restrict__ W1, ushort* __restrict__ W1T,
    const float* __restrict__ W2, ushort* __restrict__ W2T) {
  __shared__ int s[NBUCK];
  __shared__ int doff[NBUCK];
  __shared__ int dcur[NBUCK];
  int tid = threadIdx.x;
  if (blockIdx.x < NBUCK) {
    int b = blockIdx.x;
    int c = gcur[tid];
    if (c > BCAP) c = BCAP;
    s[tid] = c;
    for (int off = 1; off < 256; off <<= 1) {
      __syncthreads();
      int t = (tid >= off) ? s[tid - off] : 0;
      __syncthreads();
      s[tid] += t;
    }
    __syncthreads();
    int my_base = (b > 0) ? s[b - 1] : 0;  // exclusive prefix
    int count = s[b] - my_base;

    dcur[tid] = 0;
    __syncthreads();
    const unsigned* eb = &ebuf[b * BCAP];
    for (int e = tid; e < count; e += 256) {
      atomicAdd(&dcur[eb[e] >> 16], 1);
    }
    __syncthreads();
    int dn = dcur[tid];
    s[tid] = dn;
    for (int off = 1; off < 256; off <<= 1) {
      __syncthreads();
      int t = (tid >= off) ? s[tid - off] : 0;
      __syncthreads();
      s[tid] += t;
    }
    __syncthreads();
    doff[tid] = s[tid] - dn;  // exclusive within bucket
    int node = b * 256 + tid;
    if (node < NNODES) {
      deg[node] = dn;
      offs[node] = my_base + doff[tid];
    }
    dcur[tid] = 0;
    __syncthreads();

    for (int e = tid; e < count; e += 256) {
      unsigned v = eb[e];
      int loc = v >> 16;
      int pos = my_base + doff[loc] + atomicAdd(&dcur[loc], 1);
      ssrc[pos] = (ushort)(v & 0xffffu);
    }
    return;
  }
  // ---- cast range ----
  int t = (blockIdx.x - NBUCK) * 256 + tid;
  if (t < 1600000) {  // x -> bf16, linear layout
    float4 v = *reinterpret_cast<const float4*>(&x[t * 4]);
    ushort4 o;
    o.x = f32_to_bf16_rne(v.x);
    o.y = f32_to_bf16_rne(v.y);
    o.z = f32_to_bf16_rne(v.z);
    o.w = f32_to_bf16_rne(v.w);
    *reinterpret_cast<ushort4*>(&xh[t * 4]) = o;
    return;
  }
  t -= 1600000;
  if (t < 16384) {  // W1T[c][k] = bf16(W1[k][c])
    int c = t >> 7, k = t & 127;
    W1T[c * 128 + k] = f32_to_bf16_rne(W1[k * 128 + c]);
    return;
  }
  t -= 16384;
  if (t < 2048) {  // W2T[c][k] = bf16(W2[k][c])
    int c = t >> 7, k = t & 127;
    W2T[c * 128 + k] = f32_to_bf16_rne(W2[k * 16 + c]);
  }
}

// ------ fused layer1 + dense (R5-proven; fused1 floor = 43.1us measured) ---
// Gather: 3125 blocks, 16 lanes/node, 4 edge streams -> LDS agg tile.
// GEMM1: 4 waves x 2 column-tiles; epilogue (b1, relu, 1-bit mask) -> ht.
// GEMM2: wave 0, 4 MFMAs -> zh. 3125*16 = 50000 exactly: no tail.
#define HT_STRIDE 132  // shorts; 2-way bank aliasing on b64/b128 (free)
__global__ __launch_bounds__(256) void k_fused1(
    const ushort* __restrict__ xh, const int* __restrict__ offs,
    const int* __restrict__ deg, const ushort* __restrict__ ssrc,
    const ushort* __restrict__ W1T, const float* __restrict__ b1,
    const unsigned* __restrict__ maskb, const ushort* __restrict__ W2T,
    ushort* __restrict__ zh) {
  __shared__ ushort sh[16 * HT_STRIDE];  // agg tile [node][ch]
  __shared__ ushort ht[16 * HT_STRIDE];  // h tile [node][ch]
  int tid = threadIdx.x;
  int grp = tid >> 4;   // node within block (0..15)
  int l16 = tid & 15;   // channel group: ch [8*l16, 8*l16+8)
  int nw = blockIdx.x * 16;
  int n = nw + grp;     // always < NNODES (3125*16 == 50000)
  int start = offs[n];
  int d = deg[n];
  const ushort* base = xh + l16 * 8;
  float a0[8] = {0,0,0,0,0,0,0,0};
  float a1[8] = {0,0,0,0,0,0,0,0};
  float a2[8] = {0,0,0,0,0,0,0,0};
  float a3[8] = {0,0,0,0,0,0,0,0};
  int j = 0;
  for (; j + 3 < d; j += 4) {
    int s0 = ssrc[start + j + 0];
    int s1 = ssrc[start + j + 1];
    int s2 = ssrc[start + j + 2];
    int s3 = ssrc[start + j + 3];
    uint4 u0 = *reinterpret_cast<const uint4*>(base + s0 * FDIM);
    uint4 u1 = *reinterpret_cast<const uint4*>(base + s1 * FDIM);
    uint4 u2 = *reinterpret_cast<const uint4*>(base + s2 * FDIM);
    uint4 u3 = *reinterpret_cast<const uint4*>(base + s3 * FDIM);
    a0[0] += bf_lo(u0.x); a0[1] += bf_hi(u0.x); a0[2] += bf_lo(u0.y); a0[3] += bf_hi(u0.y);
    a0[4] += bf_lo(u0.z); a0[5] += bf_hi(u0.z); a0[6] += bf_lo(u0.w); a0[7] += bf_hi(u0.w);
    a1[0] += bf_lo(u1.x); a1[1] += bf_hi(u1.x); a1[2] += bf_lo(u1.y); a1[3] += bf_hi(u1.y);
    a1[4] += bf_lo(u1.z); a1[5] += bf_hi(u1.z); a1[6] += bf_lo(u1.w); a1[7] += bf_hi(u1.w);
    a2[0] += bf_lo(u2.x); a2[1] += bf_hi(u2.x); a2[2] += bf_lo(u2.y); a2[3] += bf_hi(u2.y);
    a2[4] += bf_lo(u2.z); a2[5] += bf_hi(u2.z); a2[6] += bf_lo(u2.w); a2[7] += bf_hi(u2.w);
    a3[0] += bf_lo(u3.x); a3[1] += bf_hi(u3.x); a3[2] += bf_lo(u3.y); a3[3] += bf_hi(u3.y);
    a3[4] += bf_lo(u3.z); a3[5] += bf_hi(u3.z); a3[6] += bf_lo(u3.w); a3[7] += bf_hi(u3.w);
  }
  for (; j < d; ++j) {
    int s0 = ssrc[start + j];
    uint4 u0 = *reinterpret_cast<const uint4*>(base + s0 * FDIM);
    a0[0] += bf_lo(u0.x); a0[1] += bf_hi(u0.x); a0[2] += bf_lo(u0.y); a0[3] += bf_hi(u0.y);
    a0[4] += bf_lo(u0.z); a0[5] += bf_hi(u0.z); a0[6] += bf_lo(u0.w); a0[7] += bf_hi(u0.w);
  }
  float inv = 1.0f / (float)(d > 0 ? d : 1);
  unsigned r[4];
  #pragma unroll
  for (int k = 0; k < 4; ++k) {
    float e0 = (a0[2 * k] + a1[2 * k] + a2[2 * k] + a3[2 * k]) * inv;
    float e1 = (a0[2 * k + 1] + a1[2 * k + 1] + a2[2 * k + 1] + a3[2 * k + 1]) * inv;
    r[k] = (unsigned)f32_to_bf16_rne(e0) | ((unsigned)f32_to_bf16_rne(e1) << 16);
  }
  *reinterpret_cast<uint4*>(&sh[grp * HT_STRIDE + l16 * 8]) =
      (uint4){r[0], r[1], r[2], r[3]};
  __syncthreads();

  // ---- GEMM1: wave w computes ct = 2w, 2w+1 ----
  int w = tid >> 6;
  int lane = tid & 63;
  int m = lane & 15, quad = lane >> 4;
  int ct0 = 2 * w, ct1 = 2 * w + 1;

  bf16x8 af[4];
  #pragma unroll
  for (int kk = 0; kk < 4; ++kk) {
    const ushort* ap = &sh[m * HT_STRIDE + kk * 32 + quad * 8];
    ushort4 alo = *reinterpret_cast<const ushort4*>(ap);
    ushort4 ahi = *reinterpret_cast<const ushort4*>(ap + 4);
    af[kk] = (bf16x8){(short)alo.x, (short)alo.y, (short)alo.z, (short)alo.w,
                      (short)ahi.x, (short)ahi.y, (short)ahi.z, (short)ahi.w};
  }
  f32x4 acc0 = (f32x4){0.f, 0.f, 0.f, 0.f};
  f32x4 acc1 = (f32x4){0.f, 0.f, 0.f, 0.f};
  const ushort* bp0 = &W1T[(size_t)(ct0 * 16 + m) * 128 + quad * 8];
  const ushort* bp1 = &W1T[(size_t)(ct1 * 16 + m) * 128 + quad * 8];
  #pragma unroll
  for (int kk = 0; kk < 4; ++kk) {
    acc0 = __builtin_amdgcn_mfma_f32_16x16x32_bf16(
        af[kk], *reinterpret_cast<const bf16x8*>(bp0 + kk * 32), acc0, 0, 0, 0);
    acc1 = __builtin_amdgcn_mfma_f32_16x16x32_bf16(
        af[kk], *reinterpret_cast<const bf16x8*>(bp1 + kk * 32), acc1, 0, 0, 0);
  }

  // mask words for this wave's two 32-ch blocks: word index = ct>>1 = w
  unsigned mbw[4];
  #pragma unroll
  for (int rr = 0; rr < 4; ++rr) {
    mbw[rr] = maskb[(size_t)(nw + quad * 4 + rr) * 4 + w];
  }
  float bb0 = b1[ct0 * 16 + m];
  float bb1 = b1[ct1 * 16 + m];
  int sh0 = m;        // (ct0&1)=0 -> shift = m
  int sh1 = 16 + m;   // (ct1&1)=1 -> shift = 16+m
  #pragma unroll
  for (int rr = 0; rr < 4; ++rr) {
    float v0 = acc0[rr] + bb0;
    v0 = v0 > 0.f ? v0 : 0.f;
    v0 = ((mbw[rr] >> sh0) & 1u) ? (v0 + v0) : 0.f;
    ht[(quad * 4 + rr) * HT_STRIDE + ct0 * 16 + m] = f32_to_bf16_rne(v0);
    float v1 = acc1[rr] + bb1;
    v1 = v1 > 0.f ? v1 : 0.f;
    v1 = ((mbw[rr] >> sh1) & 1u) ? (v1 + v1) : 0.f;
    ht[(quad * 4 + rr) * HT_STRIDE + ct1 * 16 + m] = f32_to_bf16_rne(v1);
  }
  __syncthreads();

  // ---- GEMM2 (wave 0 only): z_tile[16n x 16c] = ht @ W2 ----
  if (w == 0) {
    f32x4 zacc = (f32x4){0.f, 0.f, 0.f, 0.f};
    #pragma unroll
    for (int kk = 0; kk < 4; ++kk) {
      const ushort* ap = &ht[m * HT_STRIDE + kk * 32 + quad * 8];
      ushort4 alo = *reinterpret_cast<const ushort4*>(ap);
      ushort4 ahi = *reinterpret_cast<const ushort4*>(ap + 4);
      bf16x8 afr = (bf16x8){(short)alo.x, (short)alo.y, (short)alo.z, (short)alo.w,
                            (short)ahi.x, (short)ahi.y, (short)ahi.z, (short)ahi.w};
      bf16x8 b2f = *reinterpret_cast<const bf16x8*>(&W2T[m * 128 + kk * 32 + quad * 8]);
      zacc = __builtin_amdgcn_mfma_f32_16x16x32_bf16(afr, b2f, zacc, 0, 0, 0);
    }
    #pragma unroll
    for (int rr = 0; rr < 4; ++rr) {
      zh[(size_t)(nw + quad * 4 + rr) * 16 + m] = f32_to_bf16_rne(zacc[rr]);
    }
  }
}

// ---------------- layer 2 aggregate + bias: out = mean(z) + b2 ----------------
__global__ __launch_bounds__(256) void k_spmm2(
    const ushort* __restrict__ zh, const int* __restrict__ offs,
    const int* __restrict__ deg, const ushort* __restrict__ ssrc,
    const float* __restrict__ b2, float* __restrict__ out) {
  int tid = threadIdx.x;
  int nl = tid >> 3, c2 = tid & 7;  // node-local, channel pair
  int n = blockIdx.x * 32 + nl;
  if (n >= NNODES) return;
  int start = offs[n], d = deg[n];
  const ushort* zb = zh + c2 * 2;
  float a0 = 0.f, a1 = 0.f, b0 = 0.f, b1v = 0.f;
  float c0 = 0.f, c1 = 0.f, d0 = 0.f, d1 = 0.f;
  int j = 0;
  for (; j + 7 < d; j += 8) {
    int s0 = ssrc[start + j + 0], s1 = ssrc[start + j + 1];
    int s2 = ssrc[start + j + 2], s3 = ssrc[start + j + 3];
    int s4 = ssrc[start + j + 4], s5 = ssrc[start + j + 5];
    int s6 = ssrc[start + j + 6], s7 = ssrc[start + j + 7];
    unsigned u0 = *reinterpret_cast<const unsigned*>(zb + s0 * 16);
    unsigned u1 = *reinterpret_cast<const unsigned*>(zb + s1 * 16);
    unsigned u2 = *reinterpret_cast<const unsigned*>(zb + s2 * 16);
    unsigned u3 = *reinterpret_cast<const unsigned*>(zb + s3 * 16);
    unsigned u4 = *reinterpret_cast<const unsigned*>(zb + s4 * 16);
    unsigned u5 = *reinterpret_cast<const unsigned*>(zb + s5 * 16);
    unsigned u6 = *reinterpret_cast<const unsigned*>(zb + s6 * 16);
    unsigned u7 = *reinterpret_cast<const unsigned*>(zb + s7 * 16);
    a0 += bf_lo(u0); a1 += bf_hi(u0);
    b0 += bf_lo(u1); b1v += bf_hi(u1);
    c0 += bf_lo(u2); c1 += bf_hi(u2);
    d0 += bf_lo(u3); d1 += bf_hi(u3);
    a0 += bf_lo(u4); a1 += bf_hi(u4);
    b0 += bf_lo(u5); b1v += bf_hi(u5);
    c0 += bf_lo(u6); c1 += bf_hi(u6);
    d0 += bf_lo(u7); d1 += bf_hi(u7);
  }
  for (; j < d; ++j) {
    int s0 = ssrc[start + j];
    unsigned u0 = *reinterpret_cast<const unsigned*>(zb + s0 * 16);
    a0 += bf_lo(u0); a1 += bf_hi(u0);
  }
  float inv = 1.0f / (float)(d > 0 ? d : 1);
  float o0 = ((a0 + b0) + (c0 + d0)) * inv + b2[c2 * 2 + 0];
  float o1 = ((a1 + b1v) + (c1 + d1)) * inv + b2[c2 * 2 + 1];
  float2 o; o.x = o0; o.y = o1;
  *reinterpret_cast<float2*>(&out[(size_t)n * 16 + c2 * 2]) = o;
}

// ---------------- launch ----------------

extern "C" void kernel_launch(void* const* d_in, const int* in_sizes, int n_in,
                              void* d_out, int out_size, void* d_ws, size_t ws_size,
                              hipStream_t stream) {
  const float* x    = (const float*)d_in[0];
  const int*   ei   = (const int*)d_in[1];
  const float* W1   = (const float*)d_in[2];
  const float* b1   = (const float*)d_in[3];
  const float* W2   = (const float*)d_in[4];
  const float* b2   = (const float*)d_in[5];
  const float* mask = (const float*)d_in[6];
  float* out = (float*)d_out;

  const int* src = ei;            // edge_index[0]
  const int* dst = ei + NEDGES;   // edge_index[1]

  char* ws = (char*)d_ws;
  size_t o = 0;
  auto alloc = [&](size_t bytes) -> void* {
    void* p = ws + o;
    o += (bytes + 255) & ~(size_t)255;
    return p;
  };
  ushort*   xh    = (ushort*)alloc((size_t)NNODES * 128 * 2);
  ushort*   zh    = (ushort*)alloc((size_t)NNODES * 16 * 2);
  ushort*   W1T   = (ushort*)alloc((size_t)128 * 128 * 2);
  ushort*   W2T   = (ushort*)alloc((size_t)16 * 128 * 2);
  int*      deg   = (int*)alloc((size_t)NNODES * 4);
  int*      offs  = (int*)alloc((size_t)NNODES * 4);
  int*      gcur  = (int*)alloc((size_t)NBUCK * 4);
  unsigned* ebuf  = (unsigned*)alloc((size_t)NBUCK * BCAP * 4);
  ushort*   ssrc  = (ushort*)alloc((size_t)NEDGES * 2);
  unsigned* maskb = (unsigned*)alloc((size_t)NNODES * 4 * 4);

  int cast_blocks = (1600000 + 16384 + 2048 + 255) / 256;

  hipMemsetAsync(gcur, 0, NBUCK * sizeof(int), stream);
  k_binA<<<NBA + NMB, 256, 0, stream>>>(src, dst, gcur, ebuf, mask, maskb);
  k_binB_cast<<<NBUCK + cast_blocks, 256, 0, stream>>>(gcur, ebuf, deg, offs, ssrc,
                                                       x, xh, W1, W1T, W2, W2T);
  k_fused1<<<NNODES / 16, 256, 0, stream>>>(xh, offs, deg, ssrc,
                                            W1T, b1, maskb, W2T, zh);
  k_spmm2<<<(NNODES + 31) / 32, 256, 0, stream>>>(zh, offs, deg, ssrc, b2, out);
}